// Round 8
// baseline (332.780 us; speedup 1.0000x reference)
//
#include <hip/hip_runtime.h>
#include <hip/hip_bf16.h>

#define N_NODES 20000
#define N_EDGES 320000
#define F_IN 256
#define HID 64
#define HEADS 8
#define NCLS 64
#define D1 (HEADS * HID)   // 512

typedef __attribute__((ext_vector_type(8))) short short8;
typedef __attribute__((ext_vector_type(4))) float floatx4;
typedef __attribute__((ext_vector_type(2))) float v2f;

__device__ __forceinline__ ushort f2bf(float f) {
    unsigned u = __float_as_uint(f);
    unsigned r = (u + 0x7fffu + ((u >> 16) & 1u)) >> 16;
    return (ushort)r;
}
__device__ __forceinline__ v2f unpack2(unsigned u) {
    v2f r;
    r.x = __uint_as_float(u << 16);
    r.y = __uint_as_float(u & 0xffff0000u);
    return r;
}
// DPP-fused add: x + dpp(x); pure VALU, no LDS pipe
template <int CTRL>
__device__ __forceinline__ float dppadd(float x) {
    int y = __builtin_amdgcn_update_dpp(0, __float_as_int(x), CTRL, 0xF, 0xF, true);
    return x + __int_as_float(y);
}
// sum over 8-lane group: quad xor1, xor2, row_half_mirror
__device__ __forceinline__ float rowsum8(float x) {
    x = dppadd<0xB1>(x);     // quad_perm [1,0,3,2]
    x = dppadd<0x4E>(x);     // quad_perm [2,3,0,1]
    x = dppadd<0x141>(x);    // row_half_mirror (within 8)
    return x;
}
__device__ __forceinline__ float rowsum16(float x) {
    x = dppadd<0xB1>(x);
    x = dppadd<0x4E>(x);
    x = dppadd<0x124>(x);    // row_ror:4
    x = dppadd<0x128>(x);    // row_ror:8
    return x;
}
__device__ __forceinline__ float rowsum32(float x) {
    x = rowsum16(x);
    float t = __int_as_float(__builtin_amdgcn_ds_swizzle(__float_as_int(x), 0x401F));
    return x + t;
}

// ---------- fused preprocess: x->bf16, 4 weight transposes, dst histogram ----------
#define PB_HIST 1250
#define PB_CONV 5000
#define PB_T1   512
#define PB_T2   128
#define PB_TOTAL (PB_HIST + PB_CONV + 2 * PB_T1 + 2 * PB_T2)  // 7530
__global__ __launch_bounds__(256) void preprocess(
    const float* __restrict__ x, ushort* __restrict__ xbf,
    const float* __restrict__ Wl1, const float* __restrict__ Wr1,
    const float* __restrict__ Wl2, const float* __restrict__ Wr2,
    ushort* __restrict__ wt1, ushort* __restrict__ wt2,
    const int* __restrict__ dst, int* __restrict__ cnt) {
    int b = blockIdx.x, t = threadIdx.x;
    if (b < PB_HIST) {
        int i = b * 256 + t;
        if (i < N_EDGES) atomicAdd(&cnt[dst[i]], 1);
    } else if (b < PB_HIST + PB_CONV) {
        int i = (b - PB_HIST) * 256 + t;   // float4 index
        if (i < N_NODES * F_IN / 4) {
            float4 v = ((const float4*)x)[i];
            ushort4 o;
            o.x = f2bf(v.x); o.y = f2bf(v.y); o.z = f2bf(v.z); o.w = f2bf(v.w);
            ((ushort4*)xbf)[i] = o;
        }
    } else if (b < PB_HIST + PB_CONV + 2 * PB_T1) {
        int lb = b - PB_HIST - PB_CONV;
        const float* W = (lb < PB_T1) ? Wl1 : Wr1;
        ushort* Wt = wt1 + ((lb < PB_T1) ? 0 : D1 * F_IN);
        int i = (lb % PB_T1) * 256 + t;    // i = n*256 + k, Kd=256
        if (i < D1 * F_IN) {
            int n = i >> 8, k = i & 255;
            Wt[i] = f2bf(W[(size_t)k * D1 + n]);
        }
    } else {
        int lb = b - PB_HIST - PB_CONV - 2 * PB_T1;
        const float* W = (lb < PB_T2) ? Wl2 : Wr2;
        ushort* Wt = wt2 + ((lb < PB_T2) ? 0 : NCLS * D1);
        int i = (lb % PB_T2) * 256 + t;    // Kd=512
        if (i < NCLS * D1) {
            int n = i >> 9, k = i & 511;
            Wt[i] = f2bf(W[(size_t)k * NCLS + n]);
        }
    }
}

// ---------- single-kernel scan: 1 block, 1024 threads, 20 chunks ----------
__global__ __launch_bounds__(1024) void scan_all(const int* __restrict__ cnt,
                                                 int* __restrict__ row_ptr,
                                                 int* __restrict__ cursor) {
    __shared__ int wsum[16];
    __shared__ int s_running;
    int t = threadIdx.x, lane = t & 63, wv = t >> 6;
    if (t == 0) { s_running = 0; row_ptr[0] = 0; }
    __syncthreads();
    for (int base = 0; base < N_NODES; base += 1024) {
        int i = base + t;
        int v = (i < N_NODES) ? cnt[i] : 0;
        int x = v;
        #pragma unroll
        for (int d = 1; d < 64; d <<= 1) {
            int y = __shfl_up(x, d);
            if (lane >= d) x += y;
        }
        if (lane == 63) wsum[wv] = x;
        __syncthreads();
        int woff = 0;
        for (int k = 0; k < wv; k++) woff += wsum[k];
        int run = s_running;
        int incl = x + woff + run;
        if (i < N_NODES) {
            row_ptr[i + 1] = incl;
            cursor[i] = incl - v;
        }
        __syncthreads();
        if (t == 1023) s_running = incl;
        __syncthreads();
    }
}

// ---------- fused gemm1 (128x128 bf16 MFMA) + edge scatter ----------
#define APAD 40
#define G1_NT 8                       // 1024/128 col tiles
#define G1_MT ((N_NODES + 127) / 128) // 157
#define G1_BLOCKS (G1_NT * G1_MT)     // 1256
#define SC_BLOCKS (N_EDGES / 256)     // 1250
__global__ __launch_bounds__(256) void gemm1_scatter(
    const ushort* __restrict__ A, const ushort* __restrict__ Bt,
    ushort* __restrict__ C,
    const int* __restrict__ src, const int* __restrict__ dst,
    int* __restrict__ cursor, int* __restrict__ csr_src) {
    if (blockIdx.x >= G1_BLOCKS) {
        int i = (blockIdx.x - G1_BLOCKS) * 256 + threadIdx.x;
        if (i < N_EDGES) {
            int d = dst[i];
            int pos = atomicAdd(&cursor[d], 1);
            csr_src[pos] = src[i];
        }
        return;
    }
    const int M = N_NODES, N = 2 * D1, K = F_IN;
    __shared__ ushort As[128 * APAD];
    __shared__ ushort Bs[128 * APAD];
    int tid = threadIdx.x;
    int rowBase = (blockIdx.x >> 3) * 128, colBase = (blockIdx.x & 7) * 128;
    int wave = tid >> 6, lane = tid & 63;
    int quad = lane >> 4, m16 = lane & 15;
    int rh = wave >> 1, chf = wave & 1;
    floatx4 acc[4][4];
    #pragma unroll
    for (int i = 0; i < 4; i++)
        #pragma unroll
        for (int j = 0; j < 4; j++) acc[i][j] = (floatx4){0.f, 0.f, 0.f, 0.f};

    for (int k0 = 0; k0 < K; k0 += 32) {
        #pragma unroll
        for (int i = 0; i < 2; i++) {
            int idx = i * 256 + tid;
            int r = idx >> 2, kq = (idx & 3) * 8;
            int grow = rowBase + r;
            uint4 v = make_uint4(0, 0, 0, 0);
            if (grow < M) v = *(const uint4*)(A + (size_t)grow * K + k0 + kq);
            *(uint4*)&As[r * APAD + kq] = v;
            uint4 w = *(const uint4*)(Bt + (size_t)(colBase + r) * K + k0 + kq);
            *(uint4*)&Bs[r * APAD + kq] = w;
        }
        __syncthreads();
        short8 af[4], bfr[4];
        #pragma unroll
        for (int i = 0; i < 4; i++)
            af[i] = *(short8*)&As[(rh * 64 + i * 16 + m16) * APAD + quad * 8];
        #pragma unroll
        for (int j = 0; j < 4; j++)
            bfr[j] = *(short8*)&Bs[(chf * 64 + j * 16 + m16) * APAD + quad * 8];
        #pragma unroll
        for (int i = 0; i < 4; i++)
            #pragma unroll
            for (int j = 0; j < 4; j++)
                acc[i][j] = __builtin_amdgcn_mfma_f32_16x16x32_bf16(af[i], bfr[j], acc[i][j], 0, 0, 0);
        __syncthreads();
    }
    #pragma unroll
    for (int i = 0; i < 4; i++)
        #pragma unroll
        for (int j = 0; j < 4; j++)
            #pragma unroll
            for (int r = 0; r < 4; r++) {
                int row = rowBase + rh * 64 + i * 16 + quad * 4 + r;
                if (row < M) C[(size_t)row * N + colBase + chf * 64 + j * 16 + m16] = f2bf(acc[i][j][r]);
            }
}

// ---------- gemm2: 32x128 tile (625 blocks, exact M fit) ----------
__global__ __launch_bounds__(256) void gemm2_32x128(
    const ushort* __restrict__ A, const ushort* __restrict__ Bt,
    ushort* __restrict__ C) {
    const int K = D1;            // 512
    __shared__ ushort As[32 * APAD];
    __shared__ ushort Bs[128 * APAD];
    int tid = threadIdx.x;
    int rowBase = blockIdx.x * 32;
    int wave = tid >> 6, lane = tid & 63;
    int quad = lane >> 4, m16 = lane & 15;
    floatx4 acc[2][2];
    #pragma unroll
    for (int i = 0; i < 2; i++)
        #pragma unroll
        for (int j = 0; j < 2; j++) acc[i][j] = (floatx4){0.f, 0.f, 0.f, 0.f};

    for (int k0 = 0; k0 < K; k0 += 32) {
        if (tid < 128) {
            int r = tid >> 2, kq = (tid & 3) * 8;
            uint4 v = *(const uint4*)(A + (size_t)(rowBase + r) * K + k0 + kq);
            *(uint4*)&As[r * APAD + kq] = v;
        }
        #pragma unroll
        for (int i = 0; i < 2; i++) {
            int idx = i * 256 + tid;
            int r = idx >> 2, kq = (idx & 3) * 8;
            uint4 v = *(const uint4*)(Bt + (size_t)r * K + k0 + kq);
            *(uint4*)&Bs[r * APAD + kq] = v;
        }
        __syncthreads();
        short8 af[2], bfr[2];
        #pragma unroll
        for (int i = 0; i < 2; i++)
            af[i] = *(short8*)&As[(i * 16 + m16) * APAD + quad * 8];
        #pragma unroll
        for (int j = 0; j < 2; j++)
            bfr[j] = *(short8*)&Bs[(wave * 32 + j * 16 + m16) * APAD + quad * 8];
        #pragma unroll
        for (int i = 0; i < 2; i++)
            #pragma unroll
            for (int j = 0; j < 2; j++)
                acc[i][j] = __builtin_amdgcn_mfma_f32_16x16x32_bf16(af[i], bfr[j], acc[i][j], 0, 0, 0);
        __syncthreads();
    }
    #pragma unroll
    for (int i = 0; i < 2; i++)
        #pragma unroll
        for (int j = 0; j < 2; j++)
            #pragma unroll
            for (int r = 0; r < 4; r++) {
                int row = rowBase + i * 16 + quad * 4 + r;
                C[(size_t)row * 128 + wave * 32 + j * 16 + m16] = f2bf(acc[i][j][r]);
            }
}

// ---------- layer-1 fused attention: one WAVE per edge, 8 ch/lane ----------
// block = 128 thr = 2 waves; wave w handles edges w, w+2, ...; lane owns channels
// 8*lane..8*lane+7 (head = lane>>3, 8-lane head groups -> 3-step DPP reduction).
// att pre-scaled by log2(e) so e = exp2(score) is a single v_exp_f32.
__global__ __launch_bounds__(128) void attn_l1_fused(
    const ushort* __restrict__ xlr, const float* __restrict__ att,
    const float* __restrict__ b1,
    const int* __restrict__ row_ptr, const int* __restrict__ csr_src,
    ushort* __restrict__ h1out) {
    int d = blockIdx.x;
    int wave = threadIdx.x >> 6, lane = threadIdx.x & 63;
    int start = row_ptr[d], deg = row_ptr[d + 1] - start;

    uint4 xru = *(const uint4*)(xlr + (size_t)d * 1024 + 512 + 8 * lane);
    v2f xr01 = unpack2(xru.x), xr23 = unpack2(xru.y);
    v2f xr45 = unpack2(xru.z), xr67 = unpack2(xru.w);
    const float C6 = 0.6f * 1.44269504f, C4 = 0.4f * 1.44269504f;
    float4 atA = *(const float4*)(att + 8 * lane);
    float4 atB = *(const float4*)(att + 8 * lane + 4);
    v2f a6_01 = {C6 * atA.x, C6 * atA.y}, a4_01 = {C4 * atA.x, C4 * atA.y};
    v2f a6_23 = {C6 * atA.z, C6 * atA.w}, a4_23 = {C4 * atA.z, C4 * atA.w};
    v2f a6_45 = {C6 * atB.x, C6 * atB.y}, a4_45 = {C4 * atB.x, C4 * atB.y};
    v2f a6_67 = {C6 * atB.z, C6 * atB.w}, a4_67 = {C4 * atB.z, C4 * atB.w};

    float den = 0.f;
    v2f ac01 = {0.f, 0.f}, ac23 = {0.f, 0.f}, ac45 = {0.f, 0.f}, ac67 = {0.f, 0.f};

    int S = (deg > wave) ? ((deg - wave + 1) >> 1) : 0;   // edges this wave handles
    if (S > 0) {
        uint4 buf[4];
        #pragma unroll
        for (int j = 0; j < 4; j++) {
            int s = csr_src[start + wave + 2 * min(j, S - 1)];
            buf[j] = *(const uint4*)(xlr + (size_t)s * 1024 + 8 * lane);
        }
        for (int i = 0; i < S; i++) {
            uint4 cu = buf[i & 3];
            int ip = i + 4;
            if (ip < S) {
                int s = csr_src[start + wave + 2 * ip];
                buf[i & 3] = *(const uint4*)(xlr + (size_t)s * 1024 + 8 * lane);
            }
            v2f c01 = unpack2(cu.x), c23 = unpack2(cu.y);
            v2f c45 = unpack2(cu.z), c67 = unpack2(cu.w);
            v2f v01 = c01 + xr01, v23 = c23 + xr23;
            v2f v45 = c45 + xr45, v67 = c67 + xr67;
            v2f sp = a6_01 * v01 + a4_01 * __builtin_elementwise_abs(v01);
            sp = sp + a6_23 * v23 + a4_23 * __builtin_elementwise_abs(v23);
            sp = sp + a6_45 * v45 + a4_45 * __builtin_elementwise_abs(v45);
            sp = sp + a6_67 * v67 + a4_67 * __builtin_elementwise_abs(v67);
            float sc = sp.x + sp.y;
            sc = rowsum8(sc);                 // per-head score (8-lane groups)
            float e = exp2f(sc);
            den += e;
            v2f ev = {e, e};
            ac01 = ac01 + ev * c01; ac23 = ac23 + ev * c23;
            ac45 = ac45 + ev * c45; ac67 = ac67 + ev * c67;
        }
    }
    // combine the two waves' partials via LDS
    __shared__ float sden[128];
    __shared__ float sacc[2][64][8];
    sden[wave * 64 + lane] = den;
    float4 f0 = {ac01.x, ac01.y, ac23.x, ac23.y};
    float4 f1 = {ac45.x, ac45.y, ac67.x, ac67.y};
    *(float4*)&sacc[wave][lane][0] = f0;
    *(float4*)&sacc[wave][lane][4] = f1;
    __syncthreads();
    if (wave == 0) {
        den += sden[64 + lane];
        float4 g0 = *(float4*)&sacc[1][lane][0];
        float4 g1 = *(float4*)&sacc[1][lane][4];
        float inv = 1.f / (den + 1e-16f);
        float4 bA = *(const float4*)(b1 + 8 * lane);
        float4 bB = *(const float4*)(b1 + 8 * lane + 4);
        float o0 = (ac01.x + g0.x) * inv + bA.x;
        float o1 = (ac01.y + g0.y) * inv + bA.y;
        float o2 = (ac23.x + g0.z) * inv + bA.z;
        float o3 = (ac23.y + g0.w) * inv + bA.w;
        float o4 = (ac45.x + g1.x) * inv + bB.x;
        float o5 = (ac45.y + g1.y) * inv + bB.y;
        float o6 = (ac67.x + g1.z) * inv + bB.z;
        float o7 = (ac67.y + g1.w) * inv + bB.w;
        o0 = o0 > 0.f ? o0 : (__expf(o0) - 1.f);
        o1 = o1 > 0.f ? o1 : (__expf(o1) - 1.f);
        o2 = o2 > 0.f ? o2 : (__expf(o2) - 1.f);
        o3 = o3 > 0.f ? o3 : (__expf(o3) - 1.f);
        o4 = o4 > 0.f ? o4 : (__expf(o4) - 1.f);
        o5 = o5 > 0.f ? o5 : (__expf(o5) - 1.f);
        o6 = o6 > 0.f ? o6 : (__expf(o6) - 1.f);
        o7 = o7 > 0.f ? o7 : (__expf(o7) - 1.f);
        ushort4 h0, h1v;
        h0.x = f2bf(o0); h0.y = f2bf(o1); h0.z = f2bf(o2); h0.w = f2bf(o3);
        h1v.x = f2bf(o4); h1v.y = f2bf(o5); h1v.z = f2bf(o6); h1v.w = f2bf(o7);
        *(ushort4*)(h1out + (size_t)d * D1 + 8 * lane) = h0;
        *(ushort4*)(h1out + (size_t)d * D1 + 8 * lane + 4) = h1v;
    }
}

// ---------- layer-2 fused attention: half-wave per edge, 2 ch/lane ----------
__global__ __launch_bounds__(256) void attn_l2_fused(
    const ushort* __restrict__ ylr, const float* __restrict__ att2,
    const float* __restrict__ b2,
    const int* __restrict__ row_ptr, const int* __restrict__ csr_src,
    float* __restrict__ out) {
    int wave = threadIdx.x >> 6, lane = threadIdx.x & 63;
    int d = blockIdx.x * 4 + wave;
    if (d >= N_NODES) return;
    int half = lane >> 5, l31 = lane & 31;
    int start = row_ptr[d], deg = row_ptr[d + 1] - start;

    unsigned yru = *(const unsigned*)(ylr + (size_t)d * 128 + 64 + 2 * l31);
    v2f yr2 = unpack2(yru);
    float2 a2 = *(const float2*)(att2 + 2 * l31);
    const float C6 = 0.6f * 1.44269504f, C4 = 0.4f * 1.44269504f;
    v2f at6 = {C6 * a2.x, C6 * a2.y};
    v2f at4 = {C4 * a2.x, C4 * a2.y};

    float den = 0.f;
    v2f acc = {0.f, 0.f};

    if (deg > 0) {
        int S = (deg + 1) >> 1;
        unsigned yv[4];
        #pragma unroll
        for (int j = 0; j < 4; j++) {
            int p = min(2 * j + half, deg - 1);
            int s = csr_src[start + p];
            yv[j] = *(const unsigned*)(ylr + (size_t)s * 128 + 2 * l31);
        }
        for (int i = 0; i < S; i++) {
            unsigned cu = yv[i & 3];
            int pf = i + 4;
            if (pf < S) {
                int p = min(2 * pf + half, deg - 1);
                int s = csr_src[start + p];
                yv[i & 3] = *(const unsigned*)(ylr + (size_t)s * 128 + 2 * l31);
            }
            v2f c2 = unpack2(cu);
            v2f v = c2 + yr2;
            v2f sp = at6 * v + at4 * __builtin_elementwise_abs(v);
            float sc = sp.x + sp.y;
            sc = rowsum32(sc);
            float e = (2 * i + half < deg) ? exp2f(sc) : 0.f;
            den += e;
            v2f ev = {e, e};
            acc = acc + ev * c2;
        }
        den += __shfl_xor(den, 32);
        acc.x += __shfl_xor(acc.x, 32);
        acc.y += __shfl_xor(acc.y, 32);
    }
    if (half == 0) {
        float inv = 1.f / (den + 1e-16f);
        float2 bv = *(const float2*)(b2 + 2 * l31);
        float2 o;
        o.x = acc.x * inv + bv.x;
        o.y = acc.y * inv + bv.y;
        *(float2*)(out + (size_t)d * NCLS + 2 * l31) = o;
    }
}

extern "C" void kernel_launch(void* const* d_in, const int* in_sizes, int n_in,
                              void* d_out, int out_size, void* d_ws, size_t ws_size,
                              hipStream_t stream) {
    const float* x    = (const float*)d_in[0];
    const int*   edge = (const int*)d_in[1];
    const float* Wl1  = (const float*)d_in[2];
    const float* Wr1  = (const float*)d_in[3];
    const float* att1 = (const float*)d_in[4];
    const float* b1   = (const float*)d_in[5];
    const float* Wl2  = (const float*)d_in[6];
    const float* Wr2  = (const float*)d_in[7];
    const float* att2 = (const float*)d_in[8];
    const float* b2   = (const float*)d_in[9];
    float* out = (float*)d_out;

    const int* srcv = edge;
    const int* dstv = edge + N_EDGES;

    ushort* xbf  = (ushort*)d_ws;                        // N*256
    ushort* wt1  = xbf + (size_t)N_NODES * F_IN;         // 1024*256 (Wl1^T || Wr1^T)
    ushort* wt2  = wt1 + 2 * D1 * F_IN;                  // 128*512  (Wl2^T || Wr2^T)
    ushort* xlr  = wt2 + 2 * NCLS * D1;                  // N*1024 bf16
    ushort* h1   = xlr + (size_t)N_NODES * 2 * D1;       // N*512 bf16
    ushort* ylr  = h1 + (size_t)N_NODES * D1;            // N*128 bf16
    int* cnt     = (int*)(ylr + (size_t)N_NODES * 2 * NCLS);
    int* row_ptr = cnt + N_NODES;                        // N+1
    int* cursor  = row_ptr + N_NODES + 1;                // N
    int* csr_src = cursor + N_NODES;                     // E

    hipMemsetAsync(cnt, 0, N_NODES * sizeof(int), stream);
    preprocess<<<PB_TOTAL, 256, 0, stream>>>(x, xbf, Wl1, Wr1, Wl2, Wr2, wt1, wt2, dstv, cnt);
    scan_all<<<1, 1024, 0, stream>>>(cnt, row_ptr, cursor);
    // gemm1 (xlr = xbf @ [Wl1^T||Wr1^T]) fused with CSR scatter (independent work)
    gemm1_scatter<<<G1_BLOCKS + SC_BLOCKS, 256, 0, stream>>>(
        xbf, wt1, xlr, srcv, dstv, cursor, csr_src);
    attn_l1_fused<<<N_NODES, 128, 0, stream>>>(xlr, att1, b1, row_ptr, csr_src, h1);
    gemm2_32x128<<<N_NODES / 32, 256, 0, stream>>>(h1, wt2, ylr);
    attn_l2_fused<<<(N_NODES + 3) / 4, 256, 0, stream>>>(ylr, att2, b2, row_ptr, csr_src, out);
}

// Round 10
// 227.114 us; speedup vs baseline: 1.4653x; 1.4653x over previous
//
#include <hip/hip_runtime.h>
#include <hip/hip_bf16.h>

#define N_NODES 20000
#define N_EDGES 320000
#define F_IN 256
#define HID 64
#define HEADS 8
#define NCLS 64
#define D1 (HEADS * HID)   // 512
#define SCAN_BLOCKS ((N_NODES + 255) / 256)   // 79

typedef __attribute__((ext_vector_type(8))) short short8;
typedef __attribute__((ext_vector_type(4))) float floatx4;
typedef __attribute__((ext_vector_type(2))) float v2f;

__device__ __forceinline__ ushort f2bf(float f) {
    unsigned u = __float_as_uint(f);
    unsigned r = (u + 0x7fffu + ((u >> 16) & 1u)) >> 16;
    return (ushort)r;
}
__device__ __forceinline__ v2f unpack2(unsigned u) {
    v2f r;
    r.x = __uint_as_float(u << 16);
    r.y = __uint_as_float(u & 0xffff0000u);
    return r;
}
template <int CTRL>
__device__ __forceinline__ float dppadd(float x) {
    int y = __builtin_amdgcn_update_dpp(0, __float_as_int(x), CTRL, 0xF, 0xF, true);
    return x + __int_as_float(y);
}
// sum over 8-lane group (head): quad xor1, xor2, half-mirror
__device__ __forceinline__ float rowsum8(float x) {
    x = dppadd<0xB1>(x);     // quad_perm [1,0,3,2]
    x = dppadd<0x4E>(x);     // quad_perm [2,3,0,1]
    x = dppadd<0x141>(x);    // row_half_mirror
    return x;
}
__device__ __forceinline__ float rowsum16(float x) {
    x = dppadd<0xB1>(x);
    x = dppadd<0x4E>(x);
    x = dppadd<0x124>(x);    // row_ror:4
    x = dppadd<0x128>(x);    // row_ror:8
    return x;
}
__device__ __forceinline__ float rowsum32(float x) {
    x = rowsum16(x);
    float t = __int_as_float(__builtin_amdgcn_ds_swizzle(__float_as_int(x), 0x401F));
    return x + t;
}

// ---------- fused preprocess: x->bf16, 4 weight transposes, dst histogram ----------
#define PB_HIST 1250
#define PB_CONV 5000
#define PB_T1   512
#define PB_T2   128
#define PB_TOTAL (PB_HIST + PB_CONV + 2 * PB_T1 + 2 * PB_T2)  // 7530
__global__ __launch_bounds__(256) void preprocess(
    const float* __restrict__ x, ushort* __restrict__ xbf,
    const float* __restrict__ Wl1, const float* __restrict__ Wr1,
    const float* __restrict__ Wl2, const float* __restrict__ Wr2,
    ushort* __restrict__ wt1, ushort* __restrict__ wt2,
    const int* __restrict__ dst, int* __restrict__ cnt) {
    int b = blockIdx.x, t = threadIdx.x;
    if (b < PB_HIST) {
        int i = b * 256 + t;
        if (i < N_EDGES) atomicAdd(&cnt[dst[i]], 1);
    } else if (b < PB_HIST + PB_CONV) {
        int i = (b - PB_HIST) * 256 + t;   // float4 index
        if (i < N_NODES * F_IN / 4) {
            float4 v = ((const float4*)x)[i];
            ushort4 o;
            o.x = f2bf(v.x); o.y = f2bf(v.y); o.z = f2bf(v.z); o.w = f2bf(v.w);
            ((ushort4*)xbf)[i] = o;
        }
    } else if (b < PB_HIST + PB_CONV + 2 * PB_T1) {
        int lb = b - PB_HIST - PB_CONV;
        const float* W = (lb < PB_T1) ? Wl1 : Wr1;
        ushort* Wt = wt1 + ((lb < PB_T1) ? 0 : D1 * F_IN);
        int i = (lb % PB_T1) * 256 + t;
        if (i < D1 * F_IN) {
            int n = i >> 8, k = i & 255;
            Wt[i] = f2bf(W[(size_t)k * D1 + n]);
        }
    } else {
        int lb = b - PB_HIST - PB_CONV - 2 * PB_T1;
        const float* W = (lb < PB_T2) ? Wl2 : Wr2;
        ushort* Wt = wt2 + ((lb < PB_T2) ? 0 : NCLS * D1);
        int i = (lb % PB_T2) * 256 + t;
        if (i < NCLS * D1) {
            int n = i >> 9, k = i & 511;
            Wt[i] = f2bf(W[(size_t)k * NCLS + n]);
        }
    }
}

// ---------- CSR scan (parallel 2-kernel) + scatter ----------
__global__ __launch_bounds__(256) void scan_local(const int* __restrict__ cnt,
                                                  int* __restrict__ pscan,
                                                  int* __restrict__ bsum, int n) {
    int tid = threadIdx.x;
    int i = blockIdx.x * 256 + tid;
    int lane = tid & 63, wave = tid >> 6;
    int v = (i < n) ? cnt[i] : 0;
    int x = v;
    #pragma unroll
    for (int d = 1; d < 64; d <<= 1) {
        int y = __shfl_up(x, d);
        if (lane >= d) x += y;
    }
    __shared__ int wsum[4];
    if (lane == 63) wsum[wave] = x;
    __syncthreads();
    int woff = 0;
    for (int w2 = 0; w2 < wave; w2++) woff += wsum[w2];
    int incl = x + woff;
    if (i < n) pscan[i] = incl;
    if (tid == 255) bsum[blockIdx.x] = incl;
}

__global__ __launch_bounds__(256) void scan_finalize(const int* __restrict__ cnt,
                                                     const int* __restrict__ pscan,
                                                     const int* __restrict__ bsum,
                                                     int* __restrict__ row_ptr,
                                                     int* __restrict__ cursor, int n) {
    int t = threadIdx.x;
    int lane = t & 63, wave = t >> 6;
    int v = (t < SCAN_BLOCKS && t < blockIdx.x) ? bsum[t] : 0;
    #pragma unroll
    for (int mask = 1; mask < 64; mask <<= 1) v += __shfl_xor(v, mask);
    __shared__ int ws[4];
    __shared__ int soff;
    if (lane == 0) ws[wave] = v;
    __syncthreads();
    if (t == 0) soff = ws[0] + ws[1] + ws[2] + ws[3];
    __syncthreads();
    int i = blockIdx.x * 256 + t;
    if (i < n) {
        int incl = pscan[i] + soff;
        row_ptr[i + 1] = incl;
        cursor[i] = incl - cnt[i];
    }
    if (i == 0) row_ptr[0] = 0;
}

// ---------- fused gemm1 (128x128 bf16 MFMA) + edge scatter ----------
#define APAD 40
#define G1_NT 8
#define G1_MT ((N_NODES + 127) / 128) // 157
#define G1_BLOCKS (G1_NT * G1_MT)     // 1256
#define SC_BLOCKS (N_EDGES / 256)     // 1250
__global__ __launch_bounds__(256) void gemm1_scatter(
    const ushort* __restrict__ A, const ushort* __restrict__ Bt,
    ushort* __restrict__ C,
    const int* __restrict__ src, const int* __restrict__ dst,
    int* __restrict__ cursor, int* __restrict__ csr_src) {
    if (blockIdx.x >= G1_BLOCKS) {
        int i = (blockIdx.x - G1_BLOCKS) * 256 + threadIdx.x;
        if (i < N_EDGES) {
            int d = dst[i];
            int pos = atomicAdd(&cursor[d], 1);
            csr_src[pos] = src[i];
        }
        return;
    }
    const int M = N_NODES, N = 2 * D1, K = F_IN;
    __shared__ ushort As[128 * APAD];
    __shared__ ushort Bs[128 * APAD];
    int tid = threadIdx.x;
    int rowBase = (blockIdx.x >> 3) * 128, colBase = (blockIdx.x & 7) * 128;
    int wave = tid >> 6, lane = tid & 63;
    int quad = lane >> 4, m16 = lane & 15;
    int rh = wave >> 1, chf = wave & 1;
    floatx4 acc[4][4];
    #pragma unroll
    for (int i = 0; i < 4; i++)
        #pragma unroll
        for (int j = 0; j < 4; j++) acc[i][j] = (floatx4){0.f, 0.f, 0.f, 0.f};

    for (int k0 = 0; k0 < K; k0 += 32) {
        #pragma unroll
        for (int i = 0; i < 2; i++) {
            int idx = i * 256 + tid;
            int r = idx >> 2, kq = (idx & 3) * 8;
            int grow = rowBase + r;
            uint4 v = make_uint4(0, 0, 0, 0);
            if (grow < M) v = *(const uint4*)(A + (size_t)grow * K + k0 + kq);
            *(uint4*)&As[r * APAD + kq] = v;
            uint4 w = *(const uint4*)(Bt + (size_t)(colBase + r) * K + k0 + kq);
            *(uint4*)&Bs[r * APAD + kq] = w;
        }
        __syncthreads();
        short8 af[4], bfr[4];
        #pragma unroll
        for (int i = 0; i < 4; i++)
            af[i] = *(short8*)&As[(rh * 64 + i * 16 + m16) * APAD + quad * 8];
        #pragma unroll
        for (int j = 0; j < 4; j++)
            bfr[j] = *(short8*)&Bs[(chf * 64 + j * 16 + m16) * APAD + quad * 8];
        #pragma unroll
        for (int i = 0; i < 4; i++)
            #pragma unroll
            for (int j = 0; j < 4; j++)
                acc[i][j] = __builtin_amdgcn_mfma_f32_16x16x32_bf16(af[i], bfr[j], acc[i][j], 0, 0, 0);
        __syncthreads();
    }
    #pragma unroll
    for (int i = 0; i < 4; i++)
        #pragma unroll
        for (int j = 0; j < 4; j++)
            #pragma unroll
            for (int r = 0; r < 4; r++) {
                int row = rowBase + rh * 64 + i * 16 + quad * 4 + r;
                if (row < M) C[(size_t)row * N + colBase + chf * 64 + j * 16 + m16] = f2bf(acc[i][j][r]);
            }
}

// ---------- gemm2: 32x128 tile (625 blocks, exact M fit) ----------
__global__ __launch_bounds__(256) void gemm2_32x128(
    const ushort* __restrict__ A, const ushort* __restrict__ Bt,
    ushort* __restrict__ C) {
    const int K = D1;            // 512
    __shared__ ushort As[32 * APAD];
    __shared__ ushort Bs[128 * APAD];
    int tid = threadIdx.x;
    int rowBase = blockIdx.x * 32;
    int wave = tid >> 6, lane = tid & 63;
    int quad = lane >> 4, m16 = lane & 15;
    floatx4 acc[2][2];
    #pragma unroll
    for (int i = 0; i < 2; i++)
        #pragma unroll
        for (int j = 0; j < 2; j++) acc[i][j] = (floatx4){0.f, 0.f, 0.f, 0.f};

    for (int k0 = 0; k0 < K; k0 += 32) {
        if (tid < 128) {
            int r = tid >> 2, kq = (tid & 3) * 8;
            uint4 v = *(const uint4*)(A + (size_t)(rowBase + r) * K + k0 + kq);
            *(uint4*)&As[r * APAD + kq] = v;
        }
        #pragma unroll
        for (int i = 0; i < 2; i++) {
            int idx = i * 256 + tid;
            int r = idx >> 2, kq = (idx & 3) * 8;
            uint4 v = *(const uint4*)(Bt + (size_t)r * K + k0 + kq);
            *(uint4*)&Bs[r * APAD + kq] = v;
        }
        __syncthreads();
        short8 af[2], bfr[2];
        #pragma unroll
        for (int i = 0; i < 2; i++)
            af[i] = *(short8*)&As[(i * 16 + m16) * APAD + quad * 8];
        #pragma unroll
        for (int j = 0; j < 2; j++)
            bfr[j] = *(short8*)&Bs[(wave * 32 + j * 16 + m16) * APAD + quad * 8];
        #pragma unroll
        for (int i = 0; i < 2; i++)
            #pragma unroll
            for (int j = 0; j < 2; j++)
                acc[i][j] = __builtin_amdgcn_mfma_f32_16x16x32_bf16(af[i], bfr[j], acc[i][j], 0, 0, 0);
        __syncthreads();
    }
    #pragma unroll
    for (int i = 0; i < 2; i++)
        #pragma unroll
        for (int j = 0; j < 2; j++)
            #pragma unroll
            for (int r = 0; r < 4; r++) {
                int row = rowBase + i * 16 + quad * 4 + r;
                C[(size_t)row * 128 + wave * 32 + j * 16 + m16] = f2bf(acc[i][j][r]);
            }
}

// ---------- layer-1 fused attention: one WAVE per edge, 8 ch/lane ----------
// block = 128 thr = 2 waves; wave w handles edges w, w+2, ...
// NAMED register buffers with constant-index unroll — no scratch spill.
// Macro-internal locals use _-prefixed names to avoid call-site collisions.
#define L1PROC(cu, valid)                                                     \
    {                                                                         \
        v2f _c01 = unpack2((cu).x), _c23 = unpack2((cu).y);                   \
        v2f _c45 = unpack2((cu).z), _c67 = unpack2((cu).w);                   \
        v2f _v01 = _c01 + xr01, _v23 = _c23 + xr23;                           \
        v2f _v45 = _c45 + xr45, _v67 = _c67 + xr67;                           \
        v2f _sp = a6_01 * _v01 + a4_01 * __builtin_elementwise_abs(_v01);     \
        _sp = _sp + a6_23 * _v23 + a4_23 * __builtin_elementwise_abs(_v23);   \
        _sp = _sp + a6_45 * _v45 + a4_45 * __builtin_elementwise_abs(_v45);   \
        _sp = _sp + a6_67 * _v67 + a4_67 * __builtin_elementwise_abs(_v67);   \
        float _sc = _sp.x + _sp.y;                                            \
        _sc = rowsum8(_sc);                                                   \
        float _e = (valid) ? exp2f(_sc) : 0.f;                                \
        den += _e;                                                            \
        v2f _ev = {_e, _e};                                                   \
        ac01 = ac01 + _ev * _c01; ac23 = ac23 + _ev * _c23;                   \
        ac45 = ac45 + _ev * _c45; ac67 = ac67 + _ev * _c67;                   \
    }

__global__ __launch_bounds__(128) void attn_l1_fused(
    const ushort* __restrict__ xlr, const float* __restrict__ att,
    const float* __restrict__ b1,
    const int* __restrict__ row_ptr, const int* __restrict__ csr_src,
    ushort* __restrict__ h1out) {
    int d = blockIdx.x;
    int wave = threadIdx.x >> 6, lane = threadIdx.x & 63;
    int start = row_ptr[d], deg = row_ptr[d + 1] - start;

    uint4 xru = *(const uint4*)(xlr + (size_t)d * 1024 + 512 + 8 * lane);
    v2f xr01 = unpack2(xru.x), xr23 = unpack2(xru.y);
    v2f xr45 = unpack2(xru.z), xr67 = unpack2(xru.w);
    const float C6 = 0.6f * 1.44269504f, C4 = 0.4f * 1.44269504f;
    float4 atA = *(const float4*)(att + 8 * lane);
    float4 atB = *(const float4*)(att + 8 * lane + 4);
    v2f a6_01 = {C6 * atA.x, C6 * atA.y}, a4_01 = {C4 * atA.x, C4 * atA.y};
    v2f a6_23 = {C6 * atA.z, C6 * atA.w}, a4_23 = {C4 * atA.z, C4 * atA.w};
    v2f a6_45 = {C6 * atB.x, C6 * atB.y}, a4_45 = {C4 * atB.x, C4 * atB.y};
    v2f a6_67 = {C6 * atB.z, C6 * atB.w}, a4_67 = {C4 * atB.z, C4 * atB.w};

    float den = 0.f;
    v2f ac01 = {0.f, 0.f}, ac23 = {0.f, 0.f}, ac45 = {0.f, 0.f}, ac67 = {0.f, 0.f};

    int S = (deg > wave) ? ((deg - wave + 1) >> 1) : 0;   // this wave's edge count
    if (S > 0) {
        const int* cs = csr_src + start + wave;           // stride-2 edge list
        uint4 q0 = *(const uint4*)(xlr + (size_t)cs[0] * 1024 + 8 * lane);
        uint4 q1 = *(const uint4*)(xlr + (size_t)cs[2 * min(1, S - 1)] * 1024 + 8 * lane);
        uint4 q2 = *(const uint4*)(xlr + (size_t)cs[2 * min(2, S - 1)] * 1024 + 8 * lane);
        uint4 q3 = *(const uint4*)(xlr + (size_t)cs[2 * min(3, S - 1)] * 1024 + 8 * lane);
        for (int i0 = 0; i0 < S; i0 += 4) {
            uint4 e0 = q0, e1 = q1, e2 = q2, e3 = q3;
            if (i0 + 4 < S) q0 = *(const uint4*)(xlr + (size_t)cs[2 * (i0 + 4)] * 1024 + 8 * lane);
            if (i0 + 5 < S) q1 = *(const uint4*)(xlr + (size_t)cs[2 * (i0 + 5)] * 1024 + 8 * lane);
            if (i0 + 6 < S) q2 = *(const uint4*)(xlr + (size_t)cs[2 * (i0 + 6)] * 1024 + 8 * lane);
            if (i0 + 7 < S) q3 = *(const uint4*)(xlr + (size_t)cs[2 * (i0 + 7)] * 1024 + 8 * lane);
            L1PROC(e0, true)                      // i0 < S guaranteed
            L1PROC(e1, i0 + 1 < S)
            L1PROC(e2, i0 + 2 < S)
            L1PROC(e3, i0 + 3 < S)
        }
    }
    // combine the two waves' partials via LDS (wave 1 writes, stride-10 pad)
    __shared__ float sden2[64];
    __shared__ float sacc[64][10];
    if (wave == 1) {
        sden2[lane] = den;
        float4 f0 = {ac01.x, ac01.y, ac23.x, ac23.y};
        float4 f1 = {ac45.x, ac45.y, ac67.x, ac67.y};
        *(float4*)&sacc[lane][0] = f0;
        *(float4*)&sacc[lane][4] = f1;
    }
    __syncthreads();
    if (wave == 0) {
        den += sden2[lane];
        float4 g0 = *(float4*)&sacc[lane][0];
        float4 g1 = *(float4*)&sacc[lane][4];
        float inv = 1.f / (den + 1e-16f);
        float4 bA = *(const float4*)(b1 + 8 * lane);
        float4 bB = *(const float4*)(b1 + 8 * lane + 4);
        float o0 = (ac01.x + g0.x) * inv + bA.x;
        float o1 = (ac01.y + g0.y) * inv + bA.y;
        float o2 = (ac23.x + g0.z) * inv + bA.z;
        float o3 = (ac23.y + g0.w) * inv + bA.w;
        float o4 = (ac45.x + g1.x) * inv + bB.x;
        float o5 = (ac45.y + g1.y) * inv + bB.y;
        float o6 = (ac67.x + g1.z) * inv + bB.z;
        float o7 = (ac67.y + g1.w) * inv + bB.w;
        o0 = o0 > 0.f ? o0 : (__expf(o0) - 1.f);
        o1 = o1 > 0.f ? o1 : (__expf(o1) - 1.f);
        o2 = o2 > 0.f ? o2 : (__expf(o2) - 1.f);
        o3 = o3 > 0.f ? o3 : (__expf(o3) - 1.f);
        o4 = o4 > 0.f ? o4 : (__expf(o4) - 1.f);
        o5 = o5 > 0.f ? o5 : (__expf(o5) - 1.f);
        o6 = o6 > 0.f ? o6 : (__expf(o6) - 1.f);
        o7 = o7 > 0.f ? o7 : (__expf(o7) - 1.f);
        ushort4 h0, h1v;
        h0.x = f2bf(o0); h0.y = f2bf(o1); h0.z = f2bf(o2); h0.w = f2bf(o3);
        h1v.x = f2bf(o4); h1v.y = f2bf(o5); h1v.z = f2bf(o6); h1v.w = f2bf(o7);
        *(ushort4*)(h1out + (size_t)d * D1 + 8 * lane) = h0;
        *(ushort4*)(h1out + (size_t)d * D1 + 8 * lane + 4) = h1v;
    }
}

// ---------- layer-2 fused attention: half-wave per edge, 2 ch/lane ----------
// NAMED register buffers, constant-index unroll — no scratch spill.
#define L2PROC(cu, valid)                                                     \
    {                                                                         \
        v2f _cv = unpack2(cu);                                                \
        v2f _vv = _cv + yr2;                                                  \
        v2f _spv = at6 * _vv + at4 * __builtin_elementwise_abs(_vv);          \
        float _sc = _spv.x + _spv.y;                                          \
        _sc = rowsum32(_sc);                                                  \
        float _e = (valid) ? exp2f(_sc) : 0.f;                                \
        den += _e;                                                            \
        v2f _ev = {_e, _e};                                                   \
        acc = acc + _ev * _cv;                                                \
    }

__global__ __launch_bounds__(256) void attn_l2_fused(
    const ushort* __restrict__ ylr, const float* __restrict__ att2,
    const float* __restrict__ b2,
    const int* __restrict__ row_ptr, const int* __restrict__ csr_src,
    float* __restrict__ out) {
    int wave = threadIdx.x >> 6, lane = threadIdx.x & 63;
    int d = blockIdx.x * 4 + wave;
    if (d >= N_NODES) return;
    int half = lane >> 5, l31 = lane & 31;
    int start = row_ptr[d], deg = row_ptr[d + 1] - start;

    unsigned yru = *(const unsigned*)(ylr + (size_t)d * 128 + 64 + 2 * l31);
    v2f yr2 = unpack2(yru);
    float2 a2 = *(const float2*)(att2 + 2 * l31);
    const float C6 = 0.6f * 1.44269504f, C4 = 0.4f * 1.44269504f;
    v2f at6 = {C6 * a2.x, C6 * a2.y};
    v2f at4 = {C4 * a2.x, C4 * a2.y};

    float den = 0.f;
    v2f acc = {0.f, 0.f};

    if (deg > 0) {
        int S = (deg + 1) >> 1;                    // steps (2 edges/step)
        const int* cs = csr_src + start;
        int p0i = min(0 + half, deg - 1);
        int p1i = min(2 * min(1, S - 1) + half, deg - 1);
        int p2i = min(2 * min(2, S - 1) + half, deg - 1);
        int p3i = min(2 * min(3, S - 1) + half, deg - 1);
        unsigned y0 = *(const unsigned*)(ylr + (size_t)cs[p0i] * 128 + 2 * l31);
        unsigned y1 = *(const unsigned*)(ylr + (size_t)cs[p1i] * 128 + 2 * l31);
        unsigned y2 = *(const unsigned*)(ylr + (size_t)cs[p2i] * 128 + 2 * l31);
        unsigned y3 = *(const unsigned*)(ylr + (size_t)cs[p3i] * 128 + 2 * l31);
        for (int i0 = 0; i0 < S; i0 += 4) {
            unsigned u0 = y0, u1 = y1, u2 = y2, u3 = y3;
            if (i0 + 4 < S) { int p = min(2 * (i0 + 4) + half, deg - 1); y0 = *(const unsigned*)(ylr + (size_t)cs[p] * 128 + 2 * l31); }
            if (i0 + 5 < S) { int p = min(2 * (i0 + 5) + half, deg - 1); y1 = *(const unsigned*)(ylr + (size_t)cs[p] * 128 + 2 * l31); }
            if (i0 + 6 < S) { int p = min(2 * (i0 + 6) + half, deg - 1); y2 = *(const unsigned*)(ylr + (size_t)cs[p] * 128 + 2 * l31); }
            if (i0 + 7 < S) { int p = min(2 * (i0 + 7) + half, deg - 1); y3 = *(const unsigned*)(ylr + (size_t)cs[p] * 128 + 2 * l31); }
            L2PROC(u0, 2 * (i0 + 0) + half < deg)
            L2PROC(u1, 2 * (i0 + 1) + half < deg)
            L2PROC(u2, 2 * (i0 + 2) + half < deg)
            L2PROC(u3, 2 * (i0 + 3) + half < deg)
        }
        den += __shfl_xor(den, 32);
        acc.x += __shfl_xor(acc.x, 32);
        acc.y += __shfl_xor(acc.y, 32);
    }
    if (half == 0) {
        float inv = 1.f / (den + 1e-16f);
        float2 bv = *(const float2*)(b2 + 2 * l31);
        float2 o;
        o.x = acc.x * inv + bv.x;
        o.y = acc.y * inv + bv.y;
        *(float2*)(out + (size_t)d * NCLS + 2 * l31) = o;
    }
}

extern "C" void kernel_launch(void* const* d_in, const int* in_sizes, int n_in,
                              void* d_out, int out_size, void* d_ws, size_t ws_size,
                              hipStream_t stream) {
    const float* x    = (const float*)d_in[0];
    const int*   edge = (const int*)d_in[1];
    const float* Wl1  = (const float*)d_in[2];
    const float* Wr1  = (const float*)d_in[3];
    const float* att1 = (const float*)d_in[4];
    const float* b1   = (const float*)d_in[5];
    const float* Wl2  = (const float*)d_in[6];
    const float* Wr2  = (const float*)d_in[7];
    const float* att2 = (const float*)d_in[8];
    const float* b2   = (const float*)d_in[9];
    float* out = (float*)d_out;

    const int* srcv = edge;
    const int* dstv = edge + N_EDGES;

    ushort* xbf  = (ushort*)d_ws;                        // N*256
    ushort* wt1  = xbf + (size_t)N_NODES * F_IN;         // 1024*256 (Wl1^T || Wr1^T)
    ushort* wt2  = wt1 + 2 * D1 * F_IN;                  // 128*512  (Wl2^T || Wr2^T)
    ushort* xlr  = wt2 + 2 * NCLS * D1;                  // N*1024 bf16
    ushort* h1   = xlr + (size_t)N_NODES * 2 * D1;       // N*512 bf16
    ushort* ylr  = h1 + (size_t)N_NODES * D1;            // N*128 bf16
    int* cnt     = (int*)(ylr + (size_t)N_NODES * 2 * NCLS);
    int* pscan   = cnt + N_NODES;                        // N
    int* bsum    = pscan + N_NODES;                      // 128
    int* row_ptr = bsum + 128;                           // N+1
    int* cursor  = row_ptr + N_NODES + 1;                // N
    int* csr_src = cursor + N_NODES;                     // E

    hipMemsetAsync(cnt, 0, N_NODES * sizeof(int), stream);
    preprocess<<<PB_TOTAL, 256, 0, stream>>>(x, xbf, Wl1, Wr1, Wl2, Wr2, wt1, wt2, dstv, cnt);
    scan_local<<<SCAN_BLOCKS, 256, 0, stream>>>(cnt, pscan, bsum, N_NODES);
    scan_finalize<<<SCAN_BLOCKS, 256, 0, stream>>>(cnt, pscan, bsum, row_ptr, cursor, N_NODES);
    gemm1_scatter<<<G1_BLOCKS + SC_BLOCKS, 256, 0, stream>>>(
        xbf, wt1, xlr, srcv, dstv, cursor, csr_src);
    attn_l1_fused<<<N_NODES, 128, 0, stream>>>(xlr, att1, b1, row_ptr, csr_src, h1);
    gemm2_32x128<<<N_NODES / 32, 256, 0, stream>>>(h1, wt2, ylr);
    attn_l2_fused<<<(N_NODES + 3) / 4, 256, 0, stream>>>(ylr, att2, b2, row_ptr, csr_src, out);
}

// Round 11
// 223.323 us; speedup vs baseline: 1.4901x; 1.0170x over previous
//
#include <hip/hip_runtime.h>
#include <hip/hip_bf16.h>

#define N_NODES 20000
#define N_EDGES 320000
#define F_IN 256
#define HID 64
#define HEADS 8
#define NCLS 64
#define D1 (HEADS * HID)   // 512
#define SCAN_BLOCKS ((N_NODES + 255) / 256)   // 79

typedef __attribute__((ext_vector_type(8))) short short8;
typedef __attribute__((ext_vector_type(4))) float floatx4;
typedef __attribute__((ext_vector_type(2))) float v2f;

__device__ __forceinline__ ushort f2bf(float f) {
    unsigned u = __float_as_uint(f);
    unsigned r = (u + 0x7fffu + ((u >> 16) & 1u)) >> 16;
    return (ushort)r;
}
__device__ __forceinline__ v2f unpack2(unsigned u) {
    v2f r;
    r.x = __uint_as_float(u << 16);
    r.y = __uint_as_float(u & 0xffff0000u);
    return r;
}
template <int CTRL>
__device__ __forceinline__ float dppadd(float x) {
    int y = __builtin_amdgcn_update_dpp(0, __float_as_int(x), CTRL, 0xF, 0xF, true);
    return x + __int_as_float(y);
}
// sum over 8-lane group (head): quad xor1, xor2, half-mirror
__device__ __forceinline__ float rowsum8(float x) {
    x = dppadd<0xB1>(x);     // quad_perm [1,0,3,2]
    x = dppadd<0x4E>(x);     // quad_perm [2,3,0,1]
    x = dppadd<0x141>(x);    // row_half_mirror
    return x;
}
__device__ __forceinline__ float rowsum16(float x) {
    x = dppadd<0xB1>(x);
    x = dppadd<0x4E>(x);
    x = dppadd<0x124>(x);    // row_ror:4
    x = dppadd<0x128>(x);    // row_ror:8
    return x;
}
// async global->LDS 16B per lane (wave-level): LDS dest = uniform base + lane*16
__device__ __forceinline__ void async_copy16(ushort* lds, const ushort* g) {
    __builtin_amdgcn_global_load_lds(
        (const __attribute__((address_space(1))) void*)g,
        (__attribute__((address_space(3))) void*)lds, 16, 0, 0);
}

// ---------- fused preprocess: x->bf16, 4 weight transposes, dst histogram ----------
#define PB_HIST 1250
#define PB_CONV 5000
#define PB_T1   512
#define PB_T2   128
#define PB_TOTAL (PB_HIST + PB_CONV + 2 * PB_T1 + 2 * PB_T2)  // 7530
__global__ __launch_bounds__(256) void preprocess(
    const float* __restrict__ x, ushort* __restrict__ xbf,
    const float* __restrict__ Wl1, const float* __restrict__ Wr1,
    const float* __restrict__ Wl2, const float* __restrict__ Wr2,
    ushort* __restrict__ wt1, ushort* __restrict__ wt2,
    const int* __restrict__ dst, int* __restrict__ cnt) {
    int b = blockIdx.x, t = threadIdx.x;
    if (b < PB_HIST) {
        int i = b * 256 + t;
        if (i < N_EDGES) atomicAdd(&cnt[dst[i]], 1);
    } else if (b < PB_HIST + PB_CONV) {
        int i = (b - PB_HIST) * 256 + t;   // float4 index
        if (i < N_NODES * F_IN / 4) {
            float4 v = ((const float4*)x)[i];
            ushort4 o;
            o.x = f2bf(v.x); o.y = f2bf(v.y); o.z = f2bf(v.z); o.w = f2bf(v.w);
            ((ushort4*)xbf)[i] = o;
        }
    } else if (b < PB_HIST + PB_CONV + 2 * PB_T1) {
        int lb = b - PB_HIST - PB_CONV;
        const float* W = (lb < PB_T1) ? Wl1 : Wr1;
        ushort* Wt = wt1 + ((lb < PB_T1) ? 0 : D1 * F_IN);
        int i = (lb % PB_T1) * 256 + t;
        if (i < D1 * F_IN) {
            int n = i >> 8, k = i & 255;
            Wt[i] = f2bf(W[(size_t)k * D1 + n]);
        }
    } else {
        int lb = b - PB_HIST - PB_CONV - 2 * PB_T1;
        const float* W = (lb < PB_T2) ? Wl2 : Wr2;
        ushort* Wt = wt2 + ((lb < PB_T2) ? 0 : NCLS * D1);
        int i = (lb % PB_T2) * 256 + t;
        if (i < NCLS * D1) {
            int n = i >> 9, k = i & 511;
            Wt[i] = f2bf(W[(size_t)k * NCLS + n]);
        }
    }
}

// ---------- CSR scan (parallel 2-kernel) ----------
__global__ __launch_bounds__(256) void scan_local(const int* __restrict__ cnt,
                                                  int* __restrict__ pscan,
                                                  int* __restrict__ bsum, int n) {
    int tid = threadIdx.x;
    int i = blockIdx.x * 256 + tid;
    int lane = tid & 63, wave = tid >> 6;
    int v = (i < n) ? cnt[i] : 0;
    int x = v;
    #pragma unroll
    for (int d = 1; d < 64; d <<= 1) {
        int y = __shfl_up(x, d);
        if (lane >= d) x += y;
    }
    __shared__ int wsum[4];
    if (lane == 63) wsum[wave] = x;
    __syncthreads();
    int woff = 0;
    for (int w2 = 0; w2 < wave; w2++) woff += wsum[w2];
    int incl = x + woff;
    if (i < n) pscan[i] = incl;
    if (tid == 255) bsum[blockIdx.x] = incl;
}

__global__ __launch_bounds__(256) void scan_finalize(const int* __restrict__ cnt,
                                                     const int* __restrict__ pscan,
                                                     const int* __restrict__ bsum,
                                                     int* __restrict__ row_ptr,
                                                     int* __restrict__ cursor, int n) {
    int t = threadIdx.x;
    int lane = t & 63, wave = t >> 6;
    int v = (t < SCAN_BLOCKS && t < blockIdx.x) ? bsum[t] : 0;
    #pragma unroll
    for (int mask = 1; mask < 64; mask <<= 1) v += __shfl_xor(v, mask);
    __shared__ int ws[4];
    __shared__ int soff;
    if (lane == 0) ws[wave] = v;
    __syncthreads();
    if (t == 0) soff = ws[0] + ws[1] + ws[2] + ws[3];
    __syncthreads();
    int i = blockIdx.x * 256 + t;
    if (i < n) {
        int incl = pscan[i] + soff;
        row_ptr[i + 1] = incl;
        cursor[i] = incl - cnt[i];
    }
    if (i == 0) row_ptr[0] = 0;
}

// ---------- fused gemm1 (128x128 bf16 MFMA, async LDS staging) + edge scatter ----------
// Unpadded LDS rows (32 bf16 = 64 B) per the m97 pattern; global_load_lds width 16.
#define G1_NT 8
#define G1_MT ((N_NODES + 127) / 128) // 157
#define G1_BLOCKS (G1_NT * G1_MT)     // 1256
#define SC_BLOCKS (N_EDGES / 256)     // 1250
__global__ __launch_bounds__(256) void gemm1_scatter(
    const ushort* __restrict__ A, const ushort* __restrict__ Bt,
    ushort* __restrict__ C,
    const int* __restrict__ src, const int* __restrict__ dst,
    int* __restrict__ cursor, int* __restrict__ csr_src) {
    if (blockIdx.x >= G1_BLOCKS) {
        int i = (blockIdx.x - G1_BLOCKS) * 256 + threadIdx.x;
        if (i < N_EDGES) {
            int d = dst[i];
            int pos = atomicAdd(&cursor[d], 1);
            csr_src[pos] = src[i];
        }
        return;
    }
    const int M = N_NODES, N = 2 * D1, K = F_IN;
    __shared__ ushort As[128 * 32];
    __shared__ ushort Bs[128 * 32];
    int tid = threadIdx.x;
    int rowBase = (blockIdx.x >> 3) * 128, colBase = (blockIdx.x & 7) * 128;
    int wave = tid >> 6, lane = tid & 63;
    int quad = lane >> 4, m16 = lane & 15;
    int rh = wave >> 1, chf = wave & 1;
    floatx4 acc[4][4];
    #pragma unroll
    for (int i = 0; i < 4; i++)
        #pragma unroll
        for (int j = 0; j < 4; j++) acc[i][j] = (floatx4){0.f, 0.f, 0.f, 0.f};

    for (int k0 = 0; k0 < K; k0 += 32) {
        // stage A/B tiles: 512 chunks of 16 B each, 2 iters x 256 threads
        #pragma unroll
        for (int i = 0; i < 2; i++) {
            int idx = i * 256 + tid;
            int r = idx >> 2, kq = (idx & 3) * 8;
            int grow = min(rowBase + r, M - 1);           // clamp OOB rows (discarded later)
            async_copy16(&As[idx * 8], A + (size_t)grow * K + k0 + kq);
            async_copy16(&Bs[idx * 8], Bt + (size_t)(colBase + r) * K + k0 + kq);
        }
        __syncthreads();
        short8 af[4], bfr[4];
        #pragma unroll
        for (int i = 0; i < 4; i++)
            af[i] = *(short8*)&As[(rh * 64 + i * 16 + m16) * 32 + quad * 8];
        #pragma unroll
        for (int j = 0; j < 4; j++)
            bfr[j] = *(short8*)&Bs[(chf * 64 + j * 16 + m16) * 32 + quad * 8];
        #pragma unroll
        for (int i = 0; i < 4; i++)
            #pragma unroll
            for (int j = 0; j < 4; j++)
                acc[i][j] = __builtin_amdgcn_mfma_f32_16x16x32_bf16(af[i], bfr[j], acc[i][j], 0, 0, 0);
        __syncthreads();
    }
    #pragma unroll
    for (int i = 0; i < 4; i++)
        #pragma unroll
        for (int j = 0; j < 4; j++)
            #pragma unroll
            for (int r = 0; r < 4; r++) {
                int row = rowBase + rh * 64 + i * 16 + quad * 4 + r;
                if (row < M) C[(size_t)row * N + colBase + chf * 64 + j * 16 + m16] = f2bf(acc[i][j][r]);
            }
}

// ---------- gemm2: 32x128 tile, async LDS staging (625 blocks, exact M fit) ----------
__global__ __launch_bounds__(256) void gemm2_32x128(
    const ushort* __restrict__ A, const ushort* __restrict__ Bt,
    ushort* __restrict__ C) {
    const int K = D1;            // 512
    __shared__ ushort As[32 * 32];
    __shared__ ushort Bs[128 * 32];
    int tid = threadIdx.x;
    int rowBase = blockIdx.x * 32;
    int wave = tid >> 6, lane = tid & 63;
    int quad = lane >> 4, m16 = lane & 15;
    floatx4 acc[2][2];
    #pragma unroll
    for (int i = 0; i < 2; i++)
        #pragma unroll
        for (int j = 0; j < 2; j++) acc[i][j] = (floatx4){0.f, 0.f, 0.f, 0.f};

    for (int k0 = 0; k0 < K; k0 += 32) {
        if (tid < 128) {                            // waves 0,1: A tile (128 chunks)
            int r = tid >> 2, kq = (tid & 3) * 8;
            async_copy16(&As[tid * 8], A + (size_t)(rowBase + r) * K + k0 + kq);
        }
        #pragma unroll
        for (int i = 0; i < 2; i++) {               // all waves: B tile (512 chunks)
            int idx = i * 256 + tid;
            int r = idx >> 2, kq = (idx & 3) * 8;
            async_copy16(&Bs[idx * 8], Bt + (size_t)r * K + k0 + kq);
        }
        __syncthreads();
        short8 af[2], bfr[2];
        #pragma unroll
        for (int i = 0; i < 2; i++)
            af[i] = *(short8*)&As[(i * 16 + m16) * 32 + quad * 8];
        #pragma unroll
        for (int j = 0; j < 2; j++)
            bfr[j] = *(short8*)&Bs[(wave * 32 + j * 16 + m16) * 32 + quad * 8];
        #pragma unroll
        for (int i = 0; i < 2; i++)
            #pragma unroll
            for (int j = 0; j < 2; j++)
                acc[i][j] = __builtin_amdgcn_mfma_f32_16x16x32_bf16(af[i], bfr[j], acc[i][j], 0, 0, 0);
        __syncthreads();
    }
    #pragma unroll
    for (int i = 0; i < 2; i++)
        #pragma unroll
        for (int j = 0; j < 2; j++)
            #pragma unroll
            for (int r = 0; r < 4; r++) {
                int row = rowBase + i * 16 + quad * 4 + r;
                C[(size_t)row * 128 + wave * 32 + j * 16 + m16] = f2bf(acc[i][j][r]);
            }
}

// ---------- layer-1 fused attention: one WAVE per NODE, 8 ch/lane ----------
// block = 256 thr = 4 waves = 4 nodes; no LDS, no barrier, no cross-wave combine.
#define L1PROC(cu, valid)                                                     \
    {                                                                         \
        v2f _c01 = unpack2((cu).x), _c23 = unpack2((cu).y);                   \
        v2f _c45 = unpack2((cu).z), _c67 = unpack2((cu).w);                   \
        v2f _v01 = _c01 + xr01, _v23 = _c23 + xr23;                           \
        v2f _v45 = _c45 + xr45, _v67 = _c67 + xr67;                           \
        v2f _sp = a6_01 * _v01 + a4_01 * __builtin_elementwise_abs(_v01);     \
        _sp = _sp + a6_23 * _v23 + a4_23 * __builtin_elementwise_abs(_v23);   \
        _sp = _sp + a6_45 * _v45 + a4_45 * __builtin_elementwise_abs(_v45);   \
        _sp = _sp + a6_67 * _v67 + a4_67 * __builtin_elementwise_abs(_v67);   \
        float _sc = _sp.x + _sp.y;                                            \
        _sc = rowsum8(_sc);                                                   \
        float _e = (valid) ? exp2f(_sc) : 0.f;                                \
        den += _e;                                                            \
        v2f _ev = {_e, _e};                                                   \
        ac01 = ac01 + _ev * _c01; ac23 = ac23 + _ev * _c23;                   \
        ac45 = ac45 + _ev * _c45; ac67 = ac67 + _ev * _c67;                   \
    }

__global__ __launch_bounds__(256) void attn_l1_fused(
    const ushort* __restrict__ xlr, const float* __restrict__ att,
    const float* __restrict__ b1,
    const int* __restrict__ row_ptr, const int* __restrict__ csr_src,
    ushort* __restrict__ h1out) {
    int wave = threadIdx.x >> 6, lane = threadIdx.x & 63;
    int d = blockIdx.x * 4 + wave;
    int start = row_ptr[d], deg = row_ptr[d + 1] - start;

    uint4 xru = *(const uint4*)(xlr + (size_t)d * 1024 + 512 + 8 * lane);
    v2f xr01 = unpack2(xru.x), xr23 = unpack2(xru.y);
    v2f xr45 = unpack2(xru.z), xr67 = unpack2(xru.w);
    const float C6 = 0.6f * 1.44269504f, C4 = 0.4f * 1.44269504f;
    float4 atA = *(const float4*)(att + 8 * lane);
    float4 atB = *(const float4*)(att + 8 * lane + 4);
    v2f a6_01 = {C6 * atA.x, C6 * atA.y}, a4_01 = {C4 * atA.x, C4 * atA.y};
    v2f a6_23 = {C6 * atA.z, C6 * atA.w}, a4_23 = {C4 * atA.z, C4 * atA.w};
    v2f a6_45 = {C6 * atB.x, C6 * atB.y}, a4_45 = {C4 * atB.x, C4 * atB.y};
    v2f a6_67 = {C6 * atB.z, C6 * atB.w}, a4_67 = {C4 * atB.z, C4 * atB.w};

    float den = 0.f;
    v2f ac01 = {0.f, 0.f}, ac23 = {0.f, 0.f}, ac45 = {0.f, 0.f}, ac67 = {0.f, 0.f};

    if (deg > 0) {
        const int* cs = csr_src + start;
        uint4 q0 = *(const uint4*)(xlr + (size_t)cs[0] * 1024 + 8 * lane);
        uint4 q1 = *(const uint4*)(xlr + (size_t)cs[min(1, deg - 1)] * 1024 + 8 * lane);
        uint4 q2 = *(const uint4*)(xlr + (size_t)cs[min(2, deg - 1)] * 1024 + 8 * lane);
        uint4 q3 = *(const uint4*)(xlr + (size_t)cs[min(3, deg - 1)] * 1024 + 8 * lane);
        for (int i0 = 0; i0 < deg; i0 += 4) {
            uint4 e0 = q0, e1 = q1, e2 = q2, e3 = q3;
            if (i0 + 4 < deg) q0 = *(const uint4*)(xlr + (size_t)cs[i0 + 4] * 1024 + 8 * lane);
            if (i0 + 5 < deg) q1 = *(const uint4*)(xlr + (size_t)cs[i0 + 5] * 1024 + 8 * lane);
            if (i0 + 6 < deg) q2 = *(const uint4*)(xlr + (size_t)cs[i0 + 6] * 1024 + 8 * lane);
            if (i0 + 7 < deg) q3 = *(const uint4*)(xlr + (size_t)cs[i0 + 7] * 1024 + 8 * lane);
            L1PROC(e0, true)
            L1PROC(e1, i0 + 1 < deg)
            L1PROC(e2, i0 + 2 < deg)
            L1PROC(e3, i0 + 3 < deg)
        }
    }
    float inv = 1.f / (den + 1e-16f);
    float4 bA = *(const float4*)(b1 + 8 * lane);
    float4 bB = *(const float4*)(b1 + 8 * lane + 4);
    float o0 = ac01.x * inv + bA.x;
    float o1 = ac01.y * inv + bA.y;
    float o2 = ac23.x * inv + bA.z;
    float o3 = ac23.y * inv + bA.w;
    float o4 = ac45.x * inv + bB.x;
    float o5 = ac45.y * inv + bB.y;
    float o6 = ac67.x * inv + bB.z;
    float o7 = ac67.y * inv + bB.w;
    o0 = o0 > 0.f ? o0 : (__expf(o0) - 1.f);
    o1 = o1 > 0.f ? o1 : (__expf(o1) - 1.f);
    o2 = o2 > 0.f ? o2 : (__expf(o2) - 1.f);
    o3 = o3 > 0.f ? o3 : (__expf(o3) - 1.f);
    o4 = o4 > 0.f ? o4 : (__expf(o4) - 1.f);
    o5 = o5 > 0.f ? o5 : (__expf(o5) - 1.f);
    o6 = o6 > 0.f ? o6 : (__expf(o6) - 1.f);
    o7 = o7 > 0.f ? o7 : (__expf(o7) - 1.f);
    ushort4 h0, h1v;
    h0.x = f2bf(o0); h0.y = f2bf(o1); h0.z = f2bf(o2); h0.w = f2bf(o3);
    h1v.x = f2bf(o4); h1v.y = f2bf(o5); h1v.z = f2bf(o6); h1v.w = f2bf(o7);
    *(ushort4*)(h1out + (size_t)d * D1 + 8 * lane) = h0;
    *(ushort4*)(h1out + (size_t)d * D1 + 8 * lane + 4) = h1v;
}

// ---------- layer-2 fused attention: 16-lane groups, 4 edges/wave/step ----------
// wave per node; grp = lane>>4 handles edge 4i+grp; lane owns channels 4*l15..+3.
// Per-edge reduction = pure-DPP rowsum16; cross-group combine once at the end.
#define L2PROC(cu, valid)                                                     \
    {                                                                         \
        v2f _c01 = unpack2((cu).x), _c23 = unpack2((cu).y);                   \
        v2f _v01 = _c01 + yr01, _v23 = _c23 + yr23;                           \
        v2f _sp = at6_01 * _v01 + at4_01 * __builtin_elementwise_abs(_v01)    \
                + at6_23 * _v23 + at4_23 * __builtin_elementwise_abs(_v23);   \
        float _sc = _sp.x + _sp.y;                                            \
        _sc = rowsum16(_sc);                                                  \
        float _e = (valid) ? exp2f(_sc) : 0.f;                                \
        den += _e;                                                            \
        v2f _ev = {_e, _e};                                                   \
        ac01 = ac01 + _ev * _c01; ac23 = ac23 + _ev * _c23;                   \
    }

__device__ __forceinline__ float xgroup_sum(float x) {
    // sum over the 4 16-lane groups: xor16 (swizzle) + xor32 (bpermute)
    float t = __int_as_float(__builtin_amdgcn_ds_swizzle(__float_as_int(x), 0x401F));
    x += t;
    x += __shfl_xor(x, 32);
    return x;
}

__global__ __launch_bounds__(256) void attn_l2_fused(
    const ushort* __restrict__ ylr, const float* __restrict__ att2,
    const float* __restrict__ b2,
    const int* __restrict__ row_ptr, const int* __restrict__ csr_src,
    float* __restrict__ out) {
    int wave = threadIdx.x >> 6, lane = threadIdx.x & 63;
    int d = blockIdx.x * 4 + wave;
    int grp = lane >> 4, l15 = lane & 15;
    int start = row_ptr[d], deg = row_ptr[d + 1] - start;

    uint2 yru = *(const uint2*)(ylr + (size_t)d * 128 + 64 + 4 * l15);
    v2f yr01 = unpack2(yru.x), yr23 = unpack2(yru.y);
    float4 a2 = *(const float4*)(att2 + 4 * l15);
    const float C6 = 0.6f * 1.44269504f, C4 = 0.4f * 1.44269504f;
    v2f at6_01 = {C6 * a2.x, C6 * a2.y}, at4_01 = {C4 * a2.x, C4 * a2.y};
    v2f at6_23 = {C6 * a2.z, C6 * a2.w}, at4_23 = {C4 * a2.z, C4 * a2.w};

    float den = 0.f;
    v2f ac01 = {0.f, 0.f}, ac23 = {0.f, 0.f};

    if (deg > 0) {
        int S = (deg + 3) >> 2;                 // steps of 4 edges
        const int* cs = csr_src + start;
        uint2 q0 = *(const uint2*)(ylr + (size_t)cs[min(grp, deg - 1)] * 128 + 4 * l15);
        uint2 q1 = *(const uint2*)(ylr + (size_t)cs[min(min(1, S - 1) * 4 + grp, deg - 1)] * 128 + 4 * l15);
        for (int i = 0; i < S; i++) {
            uint2 cu = q0;
            q0 = q1;
            if (i + 2 < S) {
                int p = min((i + 2) * 4 + grp, deg - 1);
                q1 = *(const uint2*)(ylr + (size_t)cs[p] * 128 + 4 * l15);
            }
            L2PROC(cu, 4 * i + grp < deg)
        }
        den = xgroup_sum(den);
        ac01.x = xgroup_sum(ac01.x);
        ac01.y = xgroup_sum(ac01.y);
        ac23.x = xgroup_sum(ac23.x);
        ac23.y = xgroup_sum(ac23.y);
    }
    if (grp == 0) {
        float inv = 1.f / (den + 1e-16f);
        float4 bv = *(const float4*)(b2 + 4 * l15);
        float4 o;
        o.x = ac01.x * inv + bv.x;
        o.y = ac01.y * inv + bv.y;
        o.z = ac23.x * inv + bv.z;
        o.w = ac23.y * inv + bv.w;
        *(float4*)(out + (size_t)d * NCLS + 4 * l15) = o;
    }
}

extern "C" void kernel_launch(void* const* d_in, const int* in_sizes, int n_in,
                              void* d_out, int out_size, void* d_ws, size_t ws_size,
                              hipStream_t stream) {
    const float* x    = (const float*)d_in[0];
    const int*   edge = (const int*)d_in[1];
    const float* Wl1  = (const float*)d_in[2];
    const float* Wr1  = (const float*)d_in[3];
    const float* att1 = (const float*)d_in[4];
    const float* b1   = (const float*)d_in[5];
    const float* Wl2  = (const float*)d_in[6];
    const float* Wr2  = (const float*)d_in[7];
    const float* att2 = (const float*)d_in[8];
    const float* b2   = (const float*)d_in[9];
    float* out = (float*)d_out;

    const int* srcv = edge;
    const int* dstv = edge + N_EDGES;

    ushort* xbf  = (ushort*)d_ws;                        // N*256
    ushort* wt1  = xbf + (size_t)N_NODES * F_IN;         // 1024*256 (Wl1^T || Wr1^T)
    ushort* wt2  = wt1 + 2 * D1 * F_IN;                  // 128*512  (Wl2^T || Wr2^T)
    ushort* xlr  = wt2 + 2 * NCLS * D1;                  // N*1024 bf16
    ushort* h1   = xlr + (size_t)N_NODES * 2 * D1;       // N*512 bf16
    ushort* ylr  = h1 + (size_t)N_NODES * D1;            // N*128 bf16
    int* cnt     = (int*)(ylr + (size_t)N_NODES * 2 * NCLS);
    int* pscan   = cnt + N_NODES;                        // N
    int* bsum    = pscan + N_NODES;                      // 128
    int* row_ptr = bsum + 128;                           // N+1
    int* cursor  = row_ptr + N_NODES + 1;                // N
    int* csr_src = cursor + N_NODES;                     // E

    hipMemsetAsync(cnt, 0, N_NODES * sizeof(int), stream);
    preprocess<<<PB_TOTAL, 256, 0, stream>>>(x, xbf, Wl1, Wr1, Wl2, Wr2, wt1, wt2, dstv, cnt);
    scan_local<<<SCAN_BLOCKS, 256, 0, stream>>>(cnt, pscan, bsum, N_NODES);
    scan_finalize<<<SCAN_BLOCKS, 256, 0, stream>>>(cnt, pscan, bsum, row_ptr, cursor, N_NODES);
    gemm1_scatter<<<G1_BLOCKS + SC_BLOCKS, 256, 0, stream>>>(
        xbf, wt1, xlr, srcv, dstv, cursor, csr_src);
    attn_l1_fused<<<N_NODES / 4, 256, 0, stream>>>(xlr, att1, b1, row_ptr, csr_src, h1);
    gemm2_32x128<<<N_NODES / 32, 256, 0, stream>>>(h1, wt2, ylr);
    attn_l2_fused<<<N_NODES / 4, 256, 0, stream>>>(ylr, att2, b2, row_ptr, csr_src, out);
}

// Round 12
// 213.229 us; speedup vs baseline: 1.5607x; 1.0473x over previous
//
#include <hip/hip_runtime.h>
#include <hip/hip_bf16.h>

#define N_NODES 20000
#define N_EDGES 320000
#define F_IN 256
#define HID 64
#define HEADS 8
#define NCLS 64
#define D1 (HEADS * HID)   // 512
#define SCAN_BLOCKS ((N_NODES + 255) / 256)   // 79

typedef __attribute__((ext_vector_type(8))) short short8;
typedef __attribute__((ext_vector_type(4))) float floatx4;
typedef __attribute__((ext_vector_type(2))) float v2f;

__device__ __forceinline__ ushort f2bf(float f) {
    unsigned u = __float_as_uint(f);
    unsigned r = (u + 0x7fffu + ((u >> 16) & 1u)) >> 16;
    return (ushort)r;
}
__device__ __forceinline__ v2f unpack2(unsigned u) {
    v2f r;
    r.x = __uint_as_float(u << 16);
    r.y = __uint_as_float(u & 0xffff0000u);
    return r;
}
template <int CTRL>
__device__ __forceinline__ float dppadd(float x) {
    int y = __builtin_amdgcn_update_dpp(0, __float_as_int(x), CTRL, 0xF, 0xF, true);
    return x + __int_as_float(y);
}
__device__ __forceinline__ float rowsum16(float x) {
    x = dppadd<0xB1>(x);     // quad_perm [1,0,3,2]
    x = dppadd<0x4E>(x);     // quad_perm [2,3,0,1]
    x = dppadd<0x124>(x);    // row_ror:4
    x = dppadd<0x128>(x);    // row_ror:8
    return x;
}
// async global->LDS 16B per lane (wave-level): LDS dest = uniform base + lane*16
__device__ __forceinline__ void async_copy16(ushort* lds, const ushort* g) {
    __builtin_amdgcn_global_load_lds(
        (const __attribute__((address_space(1))) void*)g,
        (__attribute__((address_space(3))) void*)lds, 16, 0, 0);
}

// ---------- fused preprocess: x->bf16, 4 weight transposes, dst histogram ----------
#define PB_HIST 1250
#define PB_CONV 5000
#define PB_T1   512
#define PB_T2   128
#define PB_TOTAL (PB_HIST + PB_CONV + 2 * PB_T1 + 2 * PB_T2)  // 7530
__global__ __launch_bounds__(256) void preprocess(
    const float* __restrict__ x, ushort* __restrict__ xbf,
    const float* __restrict__ Wl1, const float* __restrict__ Wr1,
    const float* __restrict__ Wl2, const float* __restrict__ Wr2,
    ushort* __restrict__ wt1, ushort* __restrict__ wt2,
    const int* __restrict__ dst, int* __restrict__ cnt) {
    int b = blockIdx.x, t = threadIdx.x;
    if (b < PB_HIST) {
        int i = b * 256 + t;
        if (i < N_EDGES) atomicAdd(&cnt[dst[i]], 1);
    } else if (b < PB_HIST + PB_CONV) {
        int i = (b - PB_HIST) * 256 + t;   // float4 index
        if (i < N_NODES * F_IN / 4) {
            float4 v = ((const float4*)x)[i];
            ushort4 o;
            o.x = f2bf(v.x); o.y = f2bf(v.y); o.z = f2bf(v.z); o.w = f2bf(v.w);
            ((ushort4*)xbf)[i] = o;
        }
    } else if (b < PB_HIST + PB_CONV + 2 * PB_T1) {
        int lb = b - PB_HIST - PB_CONV;
        const float* W = (lb < PB_T1) ? Wl1 : Wr1;
        ushort* Wt = wt1 + ((lb < PB_T1) ? 0 : D1 * F_IN);
        int i = (lb % PB_T1) * 256 + t;
        if (i < D1 * F_IN) {
            int n = i >> 8, k = i & 255;
            Wt[i] = f2bf(W[(size_t)k * D1 + n]);
        }
    } else {
        int lb = b - PB_HIST - PB_CONV - 2 * PB_T1;
        const float* W = (lb < PB_T2) ? Wl2 : Wr2;
        ushort* Wt = wt2 + ((lb < PB_T2) ? 0 : NCLS * D1);
        int i = (lb % PB_T2) * 256 + t;
        if (i < NCLS * D1) {
            int n = i >> 9, k = i & 511;
            Wt[i] = f2bf(W[(size_t)k * NCLS + n]);
        }
    }
}

// ---------- CSR scan (parallel 2-kernel) ----------
__global__ __launch_bounds__(256) void scan_local(const int* __restrict__ cnt,
                                                  int* __restrict__ pscan,
                                                  int* __restrict__ bsum, int n) {
    int tid = threadIdx.x;
    int i = blockIdx.x * 256 + tid;
    int lane = tid & 63, wave = tid >> 6;
    int v = (i < n) ? cnt[i] : 0;
    int x = v;
    #pragma unroll
    for (int d = 1; d < 64; d <<= 1) {
        int y = __shfl_up(x, d);
        if (lane >= d) x += y;
    }
    __shared__ int wsum[4];
    if (lane == 63) wsum[wave] = x;
    __syncthreads();
    int woff = 0;
    for (int w2 = 0; w2 < wave; w2++) woff += wsum[w2];
    int incl = x + woff;
    if (i < n) pscan[i] = incl;
    if (tid == 255) bsum[blockIdx.x] = incl;
}

__global__ __launch_bounds__(256) void scan_finalize(const int* __restrict__ cnt,
                                                     const int* __restrict__ pscan,
                                                     const int* __restrict__ bsum,
                                                     int* __restrict__ row_ptr,
                                                     int* __restrict__ cursor, int n) {
    int t = threadIdx.x;
    int lane = t & 63, wave = t >> 6;
    int v = (t < SCAN_BLOCKS && t < blockIdx.x) ? bsum[t] : 0;
    #pragma unroll
    for (int mask = 1; mask < 64; mask <<= 1) v += __shfl_xor(v, mask);
    __shared__ int ws[4];
    __shared__ int soff;
    if (lane == 0) ws[wave] = v;
    __syncthreads();
    if (t == 0) soff = ws[0] + ws[1] + ws[2] + ws[3];
    __syncthreads();
    int i = blockIdx.x * 256 + t;
    if (i < n) {
        int incl = pscan[i] + soff;
        row_ptr[i + 1] = incl;
        cursor[i] = incl - cnt[i];
    }
    if (i == 0) row_ptr[0] = 0;
}

// ---------- fused gemm1 (128x128 bf16 MFMA, async LDS staging) + edge scatter ----------
#define G1_NT 8
#define G1_MT ((N_NODES + 127) / 128) // 157
#define G1_BLOCKS (G1_NT * G1_MT)     // 1256
#define SC_BLOCKS (N_EDGES / 256)     // 1250
__global__ __launch_bounds__(256) void gemm1_scatter(
    const ushort* __restrict__ A, const ushort* __restrict__ Bt,
    ushort* __restrict__ C,
    const int* __restrict__ src, const int* __restrict__ dst,
    int* __restrict__ cursor, int* __restrict__ csr_src) {
    if (blockIdx.x >= G1_BLOCKS) {
        int i = (blockIdx.x - G1_BLOCKS) * 256 + threadIdx.x;
        if (i < N_EDGES) {
            int d = dst[i];
            int pos = atomicAdd(&cursor[d], 1);
            csr_src[pos] = src[i];
        }
        return;
    }
    const int M = N_NODES, N = 2 * D1, K = F_IN;
    __shared__ ushort As[128 * 32];
    __shared__ ushort Bs[128 * 32];
    int tid = threadIdx.x;
    int rowBase = (blockIdx.x >> 3) * 128, colBase = (blockIdx.x & 7) * 128;
    int wave = tid >> 6, lane = tid & 63;
    int quad = lane >> 4, m16 = lane & 15;
    int rh = wave >> 1, chf = wave & 1;
    floatx4 acc[4][4];
    #pragma unroll
    for (int i = 0; i < 4; i++)
        #pragma unroll
        for (int j = 0; j < 4; j++) acc[i][j] = (floatx4){0.f, 0.f, 0.f, 0.f};

    for (int k0 = 0; k0 < K; k0 += 32) {
        #pragma unroll
        for (int i = 0; i < 2; i++) {
            int idx = i * 256 + tid;
            int r = idx >> 2, kq = (idx & 3) * 8;
            int grow = min(rowBase + r, M - 1);           // clamp OOB rows (discarded later)
            async_copy16(&As[idx * 8], A + (size_t)grow * K + k0 + kq);
            async_copy16(&Bs[idx * 8], Bt + (size_t)(colBase + r) * K + k0 + kq);
        }
        __syncthreads();
        short8 af[4], bfr[4];
        #pragma unroll
        for (int i = 0; i < 4; i++)
            af[i] = *(short8*)&As[(rh * 64 + i * 16 + m16) * 32 + quad * 8];
        #pragma unroll
        for (int j = 0; j < 4; j++)
            bfr[j] = *(short8*)&Bs[(chf * 64 + j * 16 + m16) * 32 + quad * 8];
        #pragma unroll
        for (int i = 0; i < 4; i++)
            #pragma unroll
            for (int j = 0; j < 4; j++)
                acc[i][j] = __builtin_amdgcn_mfma_f32_16x16x32_bf16(af[i], bfr[j], acc[i][j], 0, 0, 0);
        __syncthreads();
    }
    #pragma unroll
    for (int i = 0; i < 4; i++)
        #pragma unroll
        for (int j = 0; j < 4; j++)
            #pragma unroll
            for (int r = 0; r < 4; r++) {
                int row = rowBase + rh * 64 + i * 16 + quad * 4 + r;
                if (row < M) C[(size_t)row * N + colBase + chf * 64 + j * 16 + m16] = f2bf(acc[i][j][r]);
            }
}

// ---------- gemm2: 32x128 tile, async LDS staging (625 blocks, exact M fit) ----------
__global__ __launch_bounds__(256) void gemm2_32x128(
    const ushort* __restrict__ A, const ushort* __restrict__ Bt,
    ushort* __restrict__ C) {
    const int K = D1;            // 512
    __shared__ ushort As[32 * 32];
    __shared__ ushort Bs[128 * 32];
    int tid = threadIdx.x;
    int rowBase = blockIdx.x * 32;
    int wave = tid >> 6, lane = tid & 63;
    int quad = lane >> 4, m16 = lane & 15;
    floatx4 acc[2][2];
    #pragma unroll
    for (int i = 0; i < 2; i++)
        #pragma unroll
        for (int j = 0; j < 2; j++) acc[i][j] = (floatx4){0.f, 0.f, 0.f, 0.f};

    for (int k0 = 0; k0 < K; k0 += 32) {
        if (tid < 128) {                            // waves 0,1: A tile (128 chunks)
            int r = tid >> 2, kq = (tid & 3) * 8;
            async_copy16(&As[tid * 8], A + (size_t)(rowBase + r) * K + k0 + kq);
        }
        #pragma unroll
        for (int i = 0; i < 2; i++) {               // all waves: B tile (512 chunks)
            int idx = i * 256 + tid;
            int r = idx >> 2, kq = (idx & 3) * 8;
            async_copy16(&Bs[idx * 8], Bt + (size_t)r * K + k0 + kq);
        }
        __syncthreads();
        short8 af[2], bfr[2];
        #pragma unroll
        for (int i = 0; i < 2; i++)
            af[i] = *(short8*)&As[(i * 16 + m16) * 32 + quad * 8];
        #pragma unroll
        for (int j = 0; j < 2; j++)
            bfr[j] = *(short8*)&Bs[(wave * 32 + j * 16 + m16) * 32 + quad * 8];
        #pragma unroll
        for (int i = 0; i < 2; i++)
            #pragma unroll
            for (int j = 0; j < 2; j++)
                acc[i][j] = __builtin_amdgcn_mfma_f32_16x16x32_bf16(af[i], bfr[j], acc[i][j], 0, 0, 0);
        __syncthreads();
    }
    #pragma unroll
    for (int i = 0; i < 2; i++)
        #pragma unroll
        for (int j = 0; j < 2; j++)
            #pragma unroll
            for (int r = 0; r < 4; r++) {
                int row = rowBase + i * 16 + quad * 4 + r;
                C[(size_t)row * 128 + wave * 32 + j * 16 + m16] = f2bf(acc[i][j][r]);
            }
}

// ---------- layer-1 fused attention: R6-winning layout ----------
// 128 thr/block = 2 waves, ONE node; thread t owns channels 4t..4t+3
// (16-lane head groups -> rowsum16 DPP); depth-4 named prefetch; exp2 prescale.
#define L1PROC(cu, valid)                                                     \
    {                                                                         \
        v2f _c01 = unpack2((cu).x), _c23 = unpack2((cu).y);                   \
        v2f _v01 = _c01 + xr01, _v23 = _c23 + xr23;                           \
        v2f _sp = a6_01 * _v01 + a4_01 * __builtin_elementwise_abs(_v01)      \
                + a6_23 * _v23 + a4_23 * __builtin_elementwise_abs(_v23);     \
        float _sc = _sp.x + _sp.y;                                            \
        _sc = rowsum16(_sc);                                                  \
        float _e = (valid) ? exp2f(_sc) : 0.f;                                \
        den += _e;                                                            \
        v2f _ev = {_e, _e};                                                   \
        ac01 = ac01 + _ev * _c01; ac23 = ac23 + _ev * _c23;                   \
    }

__global__ __launch_bounds__(128) void attn_l1_fused(
    const ushort* __restrict__ xlr, const float* __restrict__ att,
    const float* __restrict__ b1,
    const int* __restrict__ row_ptr, const int* __restrict__ csr_src,
    ushort* __restrict__ h1out) {
    int d = blockIdx.x, t = threadIdx.x;
    int start = row_ptr[d], deg = row_ptr[d + 1] - start;

    uint2 xru = *(const uint2*)(xlr + (size_t)d * 1024 + 512 + 4 * t);
    v2f xr01 = unpack2(xru.x), xr23 = unpack2(xru.y);
    const float C6 = 0.6f * 1.44269504f, C4 = 0.4f * 1.44269504f;
    float4 atv = *(const float4*)(att + 4 * t);
    v2f a6_01 = {C6 * atv.x, C6 * atv.y}, a4_01 = {C4 * atv.x, C4 * atv.y};
    v2f a6_23 = {C6 * atv.z, C6 * atv.w}, a4_23 = {C4 * atv.z, C4 * atv.w};

    float den = 0.f;
    v2f ac01 = {0.f, 0.f}, ac23 = {0.f, 0.f};

    if (deg > 0) {
        const int* cs = csr_src + start;
        uint2 q0 = *(const uint2*)(xlr + (size_t)cs[0] * 1024 + 4 * t);
        uint2 q1 = *(const uint2*)(xlr + (size_t)cs[min(1, deg - 1)] * 1024 + 4 * t);
        uint2 q2 = *(const uint2*)(xlr + (size_t)cs[min(2, deg - 1)] * 1024 + 4 * t);
        uint2 q3 = *(const uint2*)(xlr + (size_t)cs[min(3, deg - 1)] * 1024 + 4 * t);
        for (int i0 = 0; i0 < deg; i0 += 4) {
            uint2 e0 = q0, e1 = q1, e2 = q2, e3 = q3;
            if (i0 + 4 < deg) q0 = *(const uint2*)(xlr + (size_t)cs[i0 + 4] * 1024 + 4 * t);
            if (i0 + 5 < deg) q1 = *(const uint2*)(xlr + (size_t)cs[i0 + 5] * 1024 + 4 * t);
            if (i0 + 6 < deg) q2 = *(const uint2*)(xlr + (size_t)cs[i0 + 6] * 1024 + 4 * t);
            if (i0 + 7 < deg) q3 = *(const uint2*)(xlr + (size_t)cs[i0 + 7] * 1024 + 4 * t);
            L1PROC(e0, true)
            L1PROC(e1, i0 + 1 < deg)
            L1PROC(e2, i0 + 2 < deg)
            L1PROC(e3, i0 + 3 < deg)
        }
    }
    float inv = 1.f / (den + 1e-16f);
    float4 bv = *(const float4*)(b1 + 4 * t);
    float o0 = ac01.x * inv + bv.x;
    float o1 = ac01.y * inv + bv.y;
    float o2 = ac23.x * inv + bv.z;
    float o3 = ac23.y * inv + bv.w;
    o0 = o0 > 0.f ? o0 : (__expf(o0) - 1.f);   // ELU
    o1 = o1 > 0.f ? o1 : (__expf(o1) - 1.f);
    o2 = o2 > 0.f ? o2 : (__expf(o2) - 1.f);
    o3 = o3 > 0.f ? o3 : (__expf(o3) - 1.f);
    ushort4 hv;
    hv.x = f2bf(o0); hv.y = f2bf(o1); hv.z = f2bf(o2); hv.w = f2bf(o3);
    *(ushort4*)(h1out + (size_t)d * D1 + 4 * t) = hv;
}

// ---------- layer-2 fused attention: 16-lane groups, 4 edges/wave/step ----------
#define L2PROC(cu, valid)                                                     \
    {                                                                         \
        v2f _c01 = unpack2((cu).x), _c23 = unpack2((cu).y);                   \
        v2f _v01 = _c01 + yr01, _v23 = _c23 + yr23;                           \
        v2f _sp = at6_01 * _v01 + at4_01 * __builtin_elementwise_abs(_v01)    \
                + at6_23 * _v23 + at4_23 * __builtin_elementwise_abs(_v23);   \
        float _sc = _sp.x + _sp.y;                                            \
        _sc = rowsum16(_sc);                                                  \
        float _e = (valid) ? exp2f(_sc) : 0.f;                                \
        den += _e;                                                            \
        v2f _ev = {_e, _e};                                                   \
        ac01 = ac01 + _ev * _c01; ac23 = ac23 + _ev * _c23;                   \
    }

__device__ __forceinline__ float xgroup_sum(float x) {
    float t = __int_as_float(__builtin_amdgcn_ds_swizzle(__float_as_int(x), 0x401F));
    x += t;
    x += __shfl_xor(x, 32);
    return x;
}

__global__ __launch_bounds__(256) void attn_l2_fused(
    const ushort* __restrict__ ylr, const float* __restrict__ att2,
    const float* __restrict__ b2,
    const int* __restrict__ row_ptr, const int* __restrict__ csr_src,
    float* __restrict__ out) {
    int wave = threadIdx.x >> 6, lane = threadIdx.x & 63;
    int d = blockIdx.x * 4 + wave;
    int grp = lane >> 4, l15 = lane & 15;
    int start = row_ptr[d], deg = row_ptr[d + 1] - start;

    uint2 yru = *(const uint2*)(ylr + (size_t)d * 128 + 64 + 4 * l15);
    v2f yr01 = unpack2(yru.x), yr23 = unpack2(yru.y);
    float4 a2 = *(const float4*)(att2 + 4 * l15);
    const float C6 = 0.6f * 1.44269504f, C4 = 0.4f * 1.44269504f;
    v2f at6_01 = {C6 * a2.x, C6 * a2.y}, at4_01 = {C4 * a2.x, C4 * a2.y};
    v2f at6_23 = {C6 * a2.z, C6 * a2.w}, at4_23 = {C4 * a2.z, C4 * a2.w};

    float den = 0.f;
    v2f ac01 = {0.f, 0.f}, ac23 = {0.f, 0.f};

    if (deg > 0) {
        int S = (deg + 3) >> 2;                 // steps of 4 edges
        const int* cs = csr_src + start;
        uint2 q0 = *(const uint2*)(ylr + (size_t)cs[min(grp, deg - 1)] * 128 + 4 * l15);
        uint2 q1 = *(const uint2*)(ylr + (size_t)cs[min(min(1, S - 1) * 4 + grp, deg - 1)] * 128 + 4 * l15);
        for (int i = 0; i < S; i++) {
            uint2 cu = q0;
            q0 = q1;
            if (i + 2 < S) {
                int p = min((i + 2) * 4 + grp, deg - 1);
                q1 = *(const uint2*)(ylr + (size_t)cs[p] * 128 + 4 * l15);
            }
            L2PROC(cu, 4 * i + grp < deg)
        }
        den = xgroup_sum(den);
        ac01.x = xgroup_sum(ac01.x);
        ac01.y = xgroup_sum(ac01.y);
        ac23.x = xgroup_sum(ac23.x);
        ac23.y = xgroup_sum(ac23.y);
    }
    if (grp == 0) {
        float inv = 1.f / (den + 1e-16f);
        float4 bv = *(const float4*)(b2 + 4 * l15);
        float4 o;
        o.x = ac01.x * inv + bv.x;
        o.y = ac01.y * inv + bv.y;
        o.z = ac23.x * inv + bv.z;
        o.w = ac23.y * inv + bv.w;
        *(float4*)(out + (size_t)d * NCLS + 4 * l15) = o;
    }
}

extern "C" void kernel_launch(void* const* d_in, const int* in_sizes, int n_in,
                              void* d_out, int out_size, void* d_ws, size_t ws_size,
                              hipStream_t stream) {
    const float* x    = (const float*)d_in[0];
    const int*   edge = (const int*)d_in[1];
    const float* Wl1  = (const float*)d_in[2];
    const float* Wr1  = (const float*)d_in[3];
    const float* att1 = (const float*)d_in[4];
    const float* b1   = (const float*)d_in[5];
    const float* Wl2  = (const float*)d_in[6];
    const float* Wr2  = (const float*)d_in[7];
    const float* att2 = (const float*)d_in[8];
    const float* b2   = (const float*)d_in[9];
    float* out = (float*)d_out;

    const int* srcv = edge;
    const int* dstv = edge + N_EDGES;

    ushort* xbf  = (ushort*)d_ws;                        // N*256
    ushort* wt1  = xbf + (size_t)N_NODES * F_IN;         // 1024*256 (Wl1^T || Wr1^T)
    ushort* wt2  = wt1 + 2 * D1 * F_IN;                  // 128*512  (Wl2^T || Wr2^T)
    ushort* xlr  = wt2 + 2 * NCLS * D1;                  // N*1024 bf16
    ushort* h1   = xlr + (size_t)N_NODES * 2 * D1;       // N*512 bf16
    ushort* ylr  = h1 + (size_t)N_NODES * D1;            // N*128 bf16
    int* cnt     = (int*)(ylr + (size_t)N_NODES * 2 * NCLS);
    int* pscan   = cnt + N_NODES;                        // N
    int* bsum    = pscan + N_NODES;                      // 128
    int* row_ptr = bsum + 128;                           // N+1
    int* cursor  = row_ptr + N_NODES + 1;                // N
    int* csr_src = cursor + N_NODES;                     // E

    hipMemsetAsync(cnt, 0, N_NODES * sizeof(int), stream);
    preprocess<<<PB_TOTAL, 256, 0, stream>>>(x, xbf, Wl1, Wr1, Wl2, Wr2, wt1, wt2, dstv, cnt);
    scan_local<<<SCAN_BLOCKS, 256, 0, stream>>>(cnt, pscan, bsum, N_NODES);
    scan_finalize<<<SCAN_BLOCKS, 256, 0, stream>>>(cnt, pscan, bsum, row_ptr, cursor, N_NODES);
    gemm1_scatter<<<G1_BLOCKS + SC_BLOCKS, 256, 0, stream>>>(
        xbf, wt1, xlr, srcv, dstv, cursor, csr_src);
    attn_l1_fused<<<N_NODES, 128, 0, stream>>>(xlr, att1, b1, row_ptr, csr_src, h1);
    gemm2_32x128<<<N_NODES / 32, 256, 0, stream>>>(h1, wt2, ylr);
    attn_l2_fused<<<N_NODES / 4, 256, 0, stream>>>(ylr, att2, b2, row_ptr, csr_src, out);
}